// Round 9
// baseline (554.238 us; speedup 1.0000x reference)
//
#include <hip/hip_runtime.h>
#include <math.h>

#define NEGINF (-INFINITY)
constexpr int Np = 4096;
constexpr int Kn = 20;
constexpr float EPSf = 1e-5f;
constexpr float SLOPE = 0.2f;

typedef __bf16 bf16x8 __attribute__((ext_vector_type(8)));
typedef float f32x4 __attribute__((ext_vector_type(4)));
typedef unsigned long long ull;
typedef unsigned int u32;
typedef unsigned short u16;

// ---------------- K1: knn1 + edgeconv1 — 32-point blocks for 2 blocks/CU ----------------
// grid (128, B), 512 thr (8 waves). Lane L = (half h = L>>5, point p = L&31).
// Slice q = w*2+h (16 slices x 256 cols) scans for point n0+p.
// thrK[32] shared via atomicMin across all 16 scanners of a point (exact: final
// merge takes top-20 of the union of the 16 per-slice lists).
// Flush check per 4 candidates (cap 16 slots, trigger >=13: worst 12+4=16 — fixes
// round-7's latent overflow where the per-16 check allowed 12+16=28 > 16 slots).
// LDS 64000 B overlay:
//   scan:   pk1 f32[16][512] @0 | pi1 u16[16][512] @32768 | thrK u32[32] @49152
//   dump:   ku u32[16*32*20] @0 (40960B) | ki u16 @40960 (20480B) | midx u16[32*20] @61440
//   gather: nbr f32[32*20*2] @0 (dump dead) | midx persists @61440
__global__ __launch_bounds__(512, 4) void k1_knn1_edge1(
    const float* __restrict__ x, const float* __restrict__ W1,
    const float* __restrict__ g1, const float* __restrict__ b1,
    const float* __restrict__ m1, const float* __restrict__ v1,
    float* __restrict__ x1, __bf16* __restrict__ x1h, __bf16* __restrict__ x1l,
    float* __restrict__ xx2)
{
  __shared__ u32 smem32[16000];   // 64000 B
  float* pk1  = (float*)smem32;                       // [16][512] f32
  u16*   pi1  = (u16*)((char*)smem32 + 32768);        // [16][512] u16
  u32*   thrK = (u32*)((char*)smem32 + 49152);        // [32]
  u32*   ku   = smem32;                               // dump keys  [16*32*20]
  u16*   ki   = (u16*)((char*)smem32 + 40960);        // dump idx   [16*32*20]
  u16*   midx = (u16*)((char*)smem32 + 61440);        // merged idx [32*20]
  float* nbr  = (float*)smem32;                       // gathered coords [32*20*2]

  const int b = blockIdx.y;
  const int n0 = blockIdx.x * 32;
  const int tid = threadIdx.x;
  const int w = tid >> 6, L = tid & 63;
  const int p = L & 31;                 // point within block
  const int q = tid >> 5;               // slice 0..15 (= w*2 + (L>>5))
  const float* __restrict__ xr = x + (size_t)b*2*Np;
  const float* __restrict__ yr = xr + Np;

  const int n = n0 + p;
  const float px = xr[n], py = yr[n];

  if (tid < 32) thrK[tid] = 0xFFFFFFFFu;
  __syncthreads();

  ull kv[20];
#pragma unroll
  for (int s = 0; s < 20; ++s) kv[s] = 0ull;
  u32 u_cut = 0xFFFFFFFFu;
  int cnt = 0;

  auto flushK = [&]() {
#pragma unroll 1
    for (int f0 = 0; f0 < 16; f0 += 4) {
      if (__all(f0 >= cnt)) break;
      float fv[4]; u32 ji[4];
#pragma unroll
      for (int u = 0; u < 4; ++u) {
        fv[u] = pk1[(f0+u)*512 + tid];
        ji[u] = pi1[(f0+u)*512 + tid];
      }
#pragma unroll
      for (int u = 0; u < 4; ++u) {
        int f = f0 + u;
        ull key = (((ull)(~__float_as_uint(fv[u]))) << 32) | (u32)~ji[u];
        if (f < cnt && key > kv[19]) {
          ull ck = key;
#pragma unroll
          for (int s = 0; s < 20; ++s) {
            bool sw = ck > kv[s];
            ull tv = kv[s];
            kv[s] = sw ? ck : kv[s];
            ck = sw ? tv : ck;
          }
        }
      }
    }
    cnt = 0;
    u32 uc = ~(u32)(kv[19] >> 32);     // 0xFFFFFFFF when <20 items (no-op for min)
    atomicMin(&thrK[p], uc);
    u_cut = thrK[p];                   // <= own uc; stale-loose reads are safe
  };

  const int base = q * 256;
#pragma unroll 1
  for (int j0 = base; j0 < base + 256; j0 += 16) {
    {
      u32 hs = thrK[p];
      u_cut = hs < u_cut ? hs : u_cut;
    }
#pragma unroll
    for (int c = 0; c < 4; ++c) {
      float4 xv = *reinterpret_cast<const float4*>(xr + j0 + c*4);  // uniform -> s_load
      float4 yv = *reinterpret_cast<const float4*>(yr + j0 + c*4);
      const float xs[4] = {xv.x, xv.y, xv.z, xv.w};
      const float ys[4] = {yv.x, yv.y, yv.z, yv.w};
#pragma unroll
      for (int r = 0; r < 4; ++r) {
        float dx = xs[r] - px, dy = ys[r] - py;
        float s = dx*dx + dy*dy;
        u32 ub = __float_as_uint(s);
        if (ub <= u_cut) {
          pk1[cnt*512 + tid] = s;
          pi1[cnt*512 + tid] = (u16)(j0 + c*4 + r);
          ++cnt;
        }
      }
      if (__any(cnt >= 13)) flushK();   // cap 16: worst 12+4=16 (per-c check)
    }
  }
  flushK();

  __syncthreads();             // pbuf/thrK dead; switch to dump layout
#pragma unroll
  for (int k = 0; k < Kn; ++k) {
    ku[((size_t)q*32 + p)*20 + k] = (u32)(kv[k] >> 32);
    ki[((size_t)q*32 + p)*20 + k] = (u16)~(u32)kv[k];   // = j (real), 0xFFFF (empty)
  }
  __syncthreads();

  if (tid < 32) {              // 16-way merge per point
    const int pp = tid;
    u32 hk_[16]; u16 hj_[16]; int pc[16];
#pragma unroll
    for (int i = 0; i < 16; ++i) {
      size_t bi = ((size_t)i*32 + pp)*20;
      hk_[i] = ku[bi]; hj_[i] = ki[bi]; pc[i] = 0;
    }
    for (int k = 0; k < Kn; ++k) {
      u32 bk = hk_[0]; u16 bj = hj_[0]; int sel = 0;
#pragma unroll
      for (int i = 1; i < 16; ++i) {
        bool better = (hk_[i] > bk) || (hk_[i] == bk && hj_[i] < bj);
        if (better) { bk = hk_[i]; bj = hj_[i]; sel = i; }
      }
      midx[pp*20 + k] = bj;
      int np_ = ++pc[sel];
      size_t bi = ((size_t)sel*32 + pp)*20;
      hk_[sel] = (np_ < 20) ? ku[bi + np_] : 0u;
      hj_[sel] = (np_ < 20) ? ki[bi + np_] : (u16)0xFFFF;
    }
  }
  __syncthreads();             // midx ready; ku/ki dead

  // parallel neighbor-coordinate gather: 32*20 (x,y) pairs into LDS
  for (int i = tid; i < 32*Kn; i += 512) {
    int j = midx[i];
    nbr[i*2]     = xr[j];      // per-lane vector gather, L1-resident coords
    nbr[i*2 + 1] = yr[j];
  }
  __syncthreads();

  // phase 3: edgeconv1 — wave w handles points w*4 .. w*4+3, lane = channel o
  const int o = L;
  const float4 w1v = reinterpret_cast<const float4*>(W1)[o];
  const float sc = g1[o] / sqrtf(v1[o] + EPSf);
  const float mo = m1[o], bo = b1[o];

  for (int pi = 0; pi < 4; ++pi) {
    const int pp = w*4 + pi;
    const int np = n0 + pp;
    const float cx0 = xr[np], cx1 = yr[np];          // uniform
    const float cterm = (w1v.z - w1v.x)*cx0 + (w1v.w - w1v.y)*cx1;
    float xm = NEGINF;
#pragma unroll
    for (int k = 0; k < Kn; ++k) {
      float2 nv = *reinterpret_cast<const float2*>(&nbr[(pp*20 + k)*2]);  // LDS broadcast
      float vv = w1v.x*nv.x + w1v.y*nv.y + cterm;
      float h = (vv - mo)*sc + bo;
      h = h >= 0.f ? h : SLOPE*h;
      xm = fmaxf(xm, h);
    }
    x1[(b*64 + o)*Np + np] = xm;
    __bf16 hb = (__bf16)xm;
    __bf16 lb = (__bf16)(xm - (float)hb);
    size_t tbase = ((size_t)b*Np + np)*64 + o;
    x1h[tbase] = hb;
    x1l[tbase] = lb;
    float s = xm*xm;
#pragma unroll
    for (int off = 1; off < 64; off <<= 1) s += __shfl_xor(s, off);
    if (L == 0) xx2[b*Np + np] = s;
  }
}

// ---------------- K2: knn2 — r3/r7-best configuration (200 µs measured), verbatim -----
__global__ __launch_bounds__(256, 2) void k2_knn2(
    const __bf16* __restrict__ xh, const __bf16* __restrict__ xl,
    const float* __restrict__ xx2, int* __restrict__ idx2)
{
  __shared__ ull smem[5120];   // 40 KB. ph1: sxx f32[4096] @0 | pk[15][256] @16384 | pi[15][256] @31744 | thr[16] @39424
                               // ph2: dump[4][64][20] @0
  float* sxx = (float*)smem;
  float* pk  = (float*)((char*)smem + 16384);   // [15][256] f32 keys, 15 KB
  u16*   pi  = (u16*)((char*)smem + 31744);     // [15][256] u16 idx, 7.5 KB
  u32*   thr = (u32*)((char*)smem + 39424);     // [16] row-shared sortable thresholds

  const int b = blockIdx.y;
  const int n0 = blockIdx.x * 16;
  const int tid = threadIdx.x;
  const int w = tid >> 6, L = tid & 63;
  const int L15 = L & 15, quad = L >> 4;

  for (int j = tid*4; j < Np; j += 1024)
    *reinterpret_cast<float4*>(&sxx[j]) = *reinterpret_cast<const float4*>(&xx2[(size_t)b*Np + j]);
  if (tid < 16) thr[tid] = 0u;

  // B operand: rows n0..n0+15
  const __bf16* Rh = xh + ((size_t)b*Np + n0)*64;
  const __bf16* Rl = xl + ((size_t)b*Np + n0)*64;
  bf16x8 rh0 = *reinterpret_cast<const bf16x8*>(Rh + L15*64 +  0 + quad*8);
  bf16x8 rh1 = *reinterpret_cast<const bf16x8*>(Rh + L15*64 + 32 + quad*8);
  bf16x8 rl0 = *reinterpret_cast<const bf16x8*>(Rl + L15*64 +  0 + quad*8);
  bf16x8 rl1 = *reinterpret_cast<const bf16x8*>(Rl + L15*64 + 32 + quad*8);

  const __bf16* Cbh = xh + (size_t)b*Np*64;
  const __bf16* Cbl = xl + (size_t)b*Np*64;

  ull kv[20];
#pragma unroll
  for (int s = 0; s < 20; ++s) kv[s] = 0ull;
  float fthresh = NEGINF;
  int cnt = 0;

  __syncthreads();   // sxx + thr ready

  auto flush = [&]() {
#pragma unroll 1
    for (int f0 = 0; f0 < 15; f0 += 4) {
      if (__all(f0 >= cnt)) break;
      float fv[4]; u32 ji[4];
#pragma unroll
      for (int u = 0; u < 4; ++u) {
        fv[u] = pk[(f0+u)*256 + tid];
        ji[u] = pi[(f0+u)*256 + tid];
      }
#pragma unroll
      for (int u = 0; u < 4; ++u) {
        int f = f0 + u;
        u32 uu = __float_as_uint(fv[u]);
        u32 hk = uu ^ ((u32)((int)uu >> 31) | 0x80000000u);
        ull key = (((ull)hk) << 32) | (u32)~ji[u];
        if (f < cnt && key > kv[19]) {
          ull ck = key;
#pragma unroll
          for (int s = 0; s < 20; ++s) {
            bool sw = ck > kv[s];
            ull tv = kv[s];
            kv[s] = sw ? ck : kv[s];
            ck = sw ? tv : ck;
          }
        }
      }
    }
    cnt = 0;
    ull t = kv[19];
    ull t2 = __shfl_xor(t, 16); t = t2 > t ? t2 : t;
    t2 = __shfl_xor(t, 32);     t = t2 > t ? t2 : t;
    if (t != 0ull && quad == 0) atomicMax(&thr[L15], (u32)(t >> 32));
    u32 hs = thr[L15];
    if (hs != 0u) {
      u32 u = (hs >> 31) ? (hs ^ 0x80000000u) : ~hs;
      fthresh = fmaxf(fthresh, __uint_as_float(u));
    }
  };

#pragma unroll 1
  for (int t = 0; t < 16; ++t) {
    {   // refresh row-shared threshold (stale-loose reads are safe)
      u32 hs = thr[L15];
      if (hs != 0u) {
        u32 u = (hs >> 31) ? (hs ^ 0x80000000u) : ~hs;
        fthresh = fmaxf(fthresh, __uint_as_float(u));
      }
    }
    const int tt = w + t*4;
    const int colbase = tt * 64;
    const __bf16* ph = Cbh + (size_t)colbase*64;
    const __bf16* pl = Cbl + (size_t)colbase*64;
    bf16x8 AH[4][2], AL[4][2];
#pragma unroll
    for (int s = 0; s < 4; ++s) {
      AH[s][0] = *reinterpret_cast<const bf16x8*>(ph + (s*16 + L15)*64 +  0 + quad*8);
      AH[s][1] = *reinterpret_cast<const bf16x8*>(ph + (s*16 + L15)*64 + 32 + quad*8);
      AL[s][0] = *reinterpret_cast<const bf16x8*>(pl + (s*16 + L15)*64 +  0 + quad*8);
      AL[s][1] = *reinterpret_cast<const bf16x8*>(pl + (s*16 + L15)*64 + 32 + quad*8);
    }

    f32x4 acc[4];
#pragma unroll
    for (int s = 0; s < 4; ++s) {
      acc[s] = (f32x4){0.f, 0.f, 0.f, 0.f};
      acc[s] = __builtin_amdgcn_mfma_f32_16x16x32_bf16(AH[s][0], rh0, acc[s], 0, 0, 0);
      acc[s] = __builtin_amdgcn_mfma_f32_16x16x32_bf16(AH[s][1], rh1, acc[s], 0, 0, 0);
      acc[s] = __builtin_amdgcn_mfma_f32_16x16x32_bf16(AH[s][0], rl0, acc[s], 0, 0, 0);
      acc[s] = __builtin_amdgcn_mfma_f32_16x16x32_bf16(AH[s][1], rl1, acc[s], 0, 0, 0);
      acc[s] = __builtin_amdgcn_mfma_f32_16x16x32_bf16(AL[s][0], rh0, acc[s], 0, 0, 0);
      acc[s] = __builtin_amdgcn_mfma_f32_16x16x32_bf16(AL[s][1], rh1, acc[s], 0, 0, 0);
    }

#pragma unroll
    for (int s = 0; s < 4; ++s) {
      float4 xv = *reinterpret_cast<const float4*>(&sxx[colbase + s*16 + quad*4]);
      const float xvr[4] = {xv.x, xv.y, xv.z, xv.w};
#pragma unroll
      for (int r = 0; r < 4; ++r) {
        float e = 2.0f*acc[s][r] - xvr[r];
        if (e >= fthresh) {
          pk[cnt*256 + tid] = e;
          pi[cnt*256 + tid] = (u16)(colbase + s*16 + quad*4 + r);
          ++cnt;
        }
      }
      if (__any(cnt >= 12)) flush();   // cap 15: max cnt 11+4=15
    }
  }
  flush();

  __syncthreads();   // sxx/pbuf dead -> dump layout
#pragma unroll
  for (int k = 0; k < Kn; ++k) smem[((size_t)w*64 + L)*20 + k] = kv[k];
  __syncthreads();

  if (tid < 16) {
    const int r = tid;
    ull h[16]; int pc[16];
#pragma unroll
    for (int i = 0; i < 16; ++i) {
      h[i] = smem[((size_t)(i>>2)*64 + (i&3)*16 + r)*20];
      pc[i] = 0;
    }
    size_t obase = ((size_t)b*Np + n0 + r)*Kn;
    for (int k = 0; k < Kn; ++k) {
      ull best = h[0]; int sel = 0;
#pragma unroll
      for (int i = 1; i < 16; ++i) if (h[i] > best) { best = h[i]; sel = i; }
      idx2[obase + k] = (int)~(u32)best;
      int np_ = ++pc[sel];
      h[sel] = (np_ < 20) ? smem[((size_t)(sel>>2)*64 + (sel&3)*16 + r)*20 + np_] : 0ull;
    }
  }
}

// ---------------- KY: precompute Za[n][o] = sc*(W2a . x1_n), Cn[n][o] ----------------
// grid (256, B): 16 points/block -> 4 blocks/CU TLP.
__global__ __launch_bounds__(256) void kY(
    const __bf16* __restrict__ xh, const __bf16* __restrict__ xl,
    const float* __restrict__ W2,
    const float* __restrict__ g2, const float* __restrict__ b2,
    const float* __restrict__ m2, const float* __restrict__ v2,
    float* __restrict__ Za, float* __restrict__ Cn)
{
  __shared__ float w2t[128*66];    // [c][o] padded, ~33 KB
  const int b = blockIdx.y;
  const int n0 = blockIdx.x * 16;
  const int tid = threadIdx.x;
  const int w = tid >> 6, L = tid & 63;

  for (int i = tid; i < 8192; i += 256) {
    int o = i >> 7, c = i & 127;
    w2t[c*66 + o] = W2[i];         // W2 row-major [64][128]
  }
  __syncthreads();

  const float sc = g2[L] / sqrtf(v2[L] + EPSf);
  const float cc = b2[L] - m2[L]*sc;

  for (int pi = 0; pi < 4; ++pi) {
    const int n = n0 + w*4 + pi;
    const size_t base = ((size_t)b*Np + n)*64;
    const float xv = (float)xh[base + L] + (float)xl[base + L];
    float ya = 0.f, yb = 0.f;
#pragma unroll
    for (int c = 0; c < 64; ++c) {
      float xc = __shfl(xv, c);
      ya += w2t[c*66 + L] * xc;          // W2[o][c]      (a-part)
      yb += w2t[(64 + c)*66 + L] * xc;   // W2[o][64+c]   (b-part)
    }
    float za = sc * ya;
    Za[base + L] = za;
    Cn[base + L] = sc * yb + cc - za;
  }
}

// ---------------- K3g: edgeconv2 gather — x2[o][n] = max_k lrelu(Za[j_k][o] + Cn[n][o]) ---
__global__ __launch_bounds__(256, 2) void k3_gather(
    const float* __restrict__ Za, const float* __restrict__ Cn,
    const int* __restrict__ idx2, float* __restrict__ x2)
{
  const int b = blockIdx.y;
  const int tid = threadIdx.x;
  const int w = tid >> 6, L = tid & 63;
  const int n = blockIdx.x*4 + w;

  const int* ip = idx2 + ((size_t)b*Np + n)*Kn;
  int jreg = (L < Kn) ? ip[L] : 0;
  const float c = Cn[((size_t)b*Np + n)*64 + L];
  float xm = NEGINF;
#pragma unroll
  for (int k = 0; k < Kn; ++k) {
    int j = __shfl(jreg, k);
    float hh = Za[((size_t)b*Np + j)*64 + L] + c;
    hh = hh >= 0.f ? hh : SLOPE*hh;
    xm = fmaxf(xm, hh);
  }
  x2[(b*64 + L)*Np + n] = xm;
}

// ---------------- K4: conv5 + per-block max over n — 8-wave version ----------------
__global__ __launch_bounds__(512) void k4_conv5max(
    const float* __restrict__ x1, const float* __restrict__ x2,
    const float* __restrict__ W5,
    const float* __restrict__ g5, const float* __restrict__ b5,
    const float* __restrict__ m5, const float* __restrict__ v5,
    float* __restrict__ partials)  // (B,128,64)
{
  const int b = blockIdx.y, nb = blockIdx.x;
  const int tid = threadIdx.x;
  const int p = tid & 63;
  const int g = __builtin_amdgcn_readfirstlane(tid >> 6);   // 0..7
  const int n = nb*64 + p;
  float xcr[128];
#pragma unroll
  for (int c = 0; c < 64; ++c) {
    xcr[c]    = x1[(b*64 + c)*Np + n];
    xcr[64+c] = x2[(b*64 + c)*Np + n];
  }
  for (int oi = 0; oi < 16; ++oi) {
    const int o = g*16 + oi;
    const float* wr = W5 + o*128;
    float dot = 0.f;
#pragma unroll
    for (int c = 0; c < 128; c += 4) {
      float4 wv = *reinterpret_cast<const float4*>(wr + c);
      dot += wv.x*xcr[c] + wv.y*xcr[c+1] + wv.z*xcr[c+2] + wv.w*xcr[c+3];
    }
    float hv = (dot - m5[o])*(g5[o]/sqrtf(v5[o]+EPSf)) + b5[o];
    hv = hv >= 0.f ? hv : SLOPE*hv;
#pragma unroll
    for (int off = 1; off < 64; off <<= 1) hv = fmaxf(hv, __shfl_xor(hv, off));
    if (p == 0) partials[(b*128 + o)*64 + nb] = hv;
  }
}

// ---------------- K5: reduce partial maxima -> gmax, then t6 = W6a * gmax ----------------
// partials row (64 floats) is contiguous -> float4 x16 instead of 64 scalar loads.
__global__ __launch_bounds__(256) void k5_reduce_t6(
    const float* __restrict__ partials, const float* __restrict__ W6,
    float* __restrict__ t6)  // (B,256)
{
  __shared__ float sg[128];
  const int b = blockIdx.x;
  const int tid = threadIdx.x;
  if (tid < 128) {
    const float4* pr = reinterpret_cast<const float4*>(partials + ((size_t)b*128 + tid)*64);
    float m = NEGINF;
#pragma unroll
    for (int w = 0; w < 16; ++w) {
      float4 v = pr[w];
      m = fmaxf(m, fmaxf(fmaxf(v.x, v.y), fmaxf(v.z, v.w)));
    }
    sg[tid] = m;
  }
  __syncthreads();
  float a = 0.f;
#pragma unroll
  for (int c = 0; c < 128; c += 4) {
    float4 wv = *reinterpret_cast<const float4*>(W6 + tid*256 + c);
    a += wv.x*sg[c] + wv.y*sg[c+1] + wv.z*sg[c+2] + wv.w*sg[c+3];
  }
  t6[b*256 + tid] = a;
}

// ---------------- K6: conv6 (W6b part + t6) + bn + lrelu + W9 dot — 8-wave version ----
__global__ __launch_bounds__(512) void k6_conv6_out(
    const float* __restrict__ x1, const float* __restrict__ x2,
    const float* __restrict__ W6, const float* __restrict__ t6,
    const float* __restrict__ g6, const float* __restrict__ b6,
    const float* __restrict__ m6, const float* __restrict__ v6,
    const float* __restrict__ W9,
    float* __restrict__ out)
{
  __shared__ float red[8][64];
  const int b = blockIdx.y, nb = blockIdx.x;
  const int tid = threadIdx.x;
  const int p = tid & 63;
  const int g = __builtin_amdgcn_readfirstlane(tid >> 6);   // 0..7
  const int n = nb*64 + p;
  float xcr[128];
#pragma unroll
  for (int c = 0; c < 64; ++c) {
    xcr[c]    = x1[(b*64 + c)*Np + n];
    xcr[64+c] = x2[(b*64 + c)*Np + n];
  }
  float oacc = 0.f;
  for (int oi = 0; oi < 32; ++oi) {
    const int o = g*32 + oi;
    const float* wr = W6 + o*256 + 128;
    float dot = t6[b*256 + o];
#pragma unroll
    for (int c = 0; c < 128; c += 4) {
      float4 wv = *reinterpret_cast<const float4*>(wr + c);
      dot += wv.x*xcr[c] + wv.y*xcr[c+1] + wv.z*xcr[c+2] + wv.w*xcr[c+3];
    }
    float hv = (dot - m6[o])*(g6[o]/sqrtf(v6[o]+EPSf)) + b6[o];
    hv = hv >= 0.f ? hv : SLOPE*hv;
    oacc += W9[o]*hv;
  }
  red[g][p] = oacc;
  __syncthreads();
  if (tid < 64) {
    float s = 0.f;
#pragma unroll
    for (int q = 0; q < 8; ++q) s += red[q][tid];
    out[b*Np + nb*64 + tid] = s;
  }
}

extern "C" void kernel_launch(void* const* d_in, const int* in_sizes, int n_in,
                              void* d_out, int out_size, void* d_ws, size_t ws_size,
                              hipStream_t stream) {
  const float* x  = (const float*)d_in[0];
  const float* W1 = (const float*)d_in[1];
  const float* g1 = (const float*)d_in[2];
  const float* b1 = (const float*)d_in[3];
  const float* m1 = (const float*)d_in[4];
  const float* v1 = (const float*)d_in[5];
  const float* W2 = (const float*)d_in[6];
  const float* g2 = (const float*)d_in[7];
  const float* b2 = (const float*)d_in[8];
  const float* m2 = (const float*)d_in[9];
  const float* v2 = (const float*)d_in[10];
  const float* W5 = (const float*)d_in[11];
  const float* g5 = (const float*)d_in[12];
  const float* b5 = (const float*)d_in[13];
  const float* m5 = (const float*)d_in[14];
  const float* v5 = (const float*)d_in[15];
  const float* W6 = (const float*)d_in[16];
  const float* g6 = (const float*)d_in[17];
  const float* b6 = (const float*)d_in[18];
  const float* m6 = (const float*)d_in[19];
  const float* v6 = (const float*)d_in[20];
  const float* W9 = (const float*)d_in[21];
  float* out = (float*)d_out;

  float* F = (float*)d_ws;
  float*  x1    = F;                         // 1048576
  float*  xx2   = F + 1048576;               // 16384
  __bf16* x1h   = (__bf16*)(F + 1064960);    // 524288 float-slots
  __bf16* x1l   = (__bf16*)(F + 1589248);    // 524288
  float*  x2    = F + 2113536;               // 1048576
  int*    idx2  = (int*)(F + 3162112);       // 327680
  float*  t6    = F + 3489792;               // 1024
  float*  parts = F + 3490816;               // 32768
  float*  Za    = F + 3523584;               // 1048576
  float*  Cn    = F + 4572160;               // 1048576   (total 22.5 MB)

  k1_knn1_edge1<<<dim3(128,4), 512, 0, stream>>>(x, W1, g1, b1, m1, v1, x1, x1h, x1l, xx2);
  k2_knn2<<<dim3(256,4), 256, 0, stream>>>(x1h, x1l, xx2, idx2);
  kY<<<dim3(256,4), 256, 0, stream>>>(x1h, x1l, W2, g2, b2, m2, v2, Za, Cn);
  k3_gather<<<dim3(1024,4), 256, 0, stream>>>(Za, Cn, idx2, x2);
  k4_conv5max<<<dim3(64,4), 512, 0, stream>>>(x1, x2, W5, g5, b5, m5, v5, parts);
  k5_reduce_t6<<<4, 256, 0, stream>>>(parts, W6, t6);
  k6_conv6_out<<<dim3(64,4), 512, 0, stream>>>(x1, x2, W6, t6, g6, b6, m6, v6, W9, out);
}

// Round 10
// 524.880 us; speedup vs baseline: 1.0559x; 1.0559x over previous
//
#include <hip/hip_runtime.h>
#include <math.h>

#define NEGINF (-INFINITY)
constexpr int Np = 4096;
constexpr int Kn = 20;
constexpr float EPSf = 1e-5f;
constexpr float SLOPE = 0.2f;

typedef __bf16 bf16x8 __attribute__((ext_vector_type(8)));
typedef float f32x4 __attribute__((ext_vector_type(4)));
typedef unsigned long long ull;
typedef unsigned int u32;
typedef unsigned short u16;

// ---------------- K1: knn1 + edgeconv1 fused — 8-wave + LDS neighbor pre-gather ----------
// r8-best configuration (537 µs total), with overflow-safe flush check (inside the
// c-loop: trigger >=13, cap 16, worst 12+4=16 — r8's per-chunk check allowed 28).
// grid (64, B), 512 thr (8 waves). Wave w scans 512 cols for the block's 64 points
// (lane L = point n0+L). Key = (~bits(d2)<<32) | ~j; cross-wave thrK via atomicMin.
// LDS 64000 B overlay:
//   scan:   pk1 f32[16][512] @0 | pi1 u16[16][512] @32768 | thrK u32[64] @49152
//   dump:   ku u32[8*64*20] @0 | ki u16[8*64*20] @40960 | midx u16[64*20] @61440
//   gather: nbr f32[64*20*2] @0 (dump dead) | midx persists @61440
__global__ __launch_bounds__(512, 2) void k1_knn1_edge1(
    const float* __restrict__ x, const float* __restrict__ W1,
    const float* __restrict__ g1, const float* __restrict__ b1,
    const float* __restrict__ m1, const float* __restrict__ v1,
    float* __restrict__ x1, __bf16* __restrict__ x1h, __bf16* __restrict__ x1l,
    float* __restrict__ xx2)
{
  __shared__ u32 smem32[16000];   // 64000 B
  float* pk1  = (float*)smem32;                       // [16][512] f32
  u16*   pi1  = (u16*)((char*)smem32 + 32768);        // [16][512] u16
  u32*   thrK = (u32*)((char*)smem32 + 49152);        // [64]
  u32*   ku   = smem32;                               // dump keys  [8*64*20]
  u16*   ki   = (u16*)((char*)smem32 + 40960);        // dump idx   [8*64*20]
  u16*   midx = (u16*)((char*)smem32 + 61440);        // merged idx [64*20]
  float* nbr  = (float*)smem32;                       // gathered coords [64*20*2]

  const int b = blockIdx.y;
  const int n0 = blockIdx.x * 64;
  const int tid = threadIdx.x;
  const int w = tid >> 6, L = tid & 63;
  const float* __restrict__ xr = x + (size_t)b*2*Np;
  const float* __restrict__ yr = xr + Np;

  const int n = n0 + L;
  const float px = xr[n], py = yr[n];

  if (tid < 64) thrK[tid] = 0xFFFFFFFFu;
  __syncthreads();

  ull kv[20];
#pragma unroll
  for (int s = 0; s < 20; ++s) kv[s] = 0ull;
  u32 u_cut = 0xFFFFFFFFu;
  int cnt = 0;

  auto flushK = [&]() {
#pragma unroll 1
    for (int f0 = 0; f0 < 16; f0 += 4) {
      if (__all(f0 >= cnt)) break;
      float fv[4]; u32 ji[4];
#pragma unroll
      for (int u = 0; u < 4; ++u) {
        fv[u] = pk1[(f0+u)*512 + tid];
        ji[u] = pi1[(f0+u)*512 + tid];
      }
#pragma unroll
      for (int u = 0; u < 4; ++u) {
        int f = f0 + u;
        ull key = (((ull)(~__float_as_uint(fv[u]))) << 32) | (u32)~ji[u];
        if (f < cnt && key > kv[19]) {
          ull ck = key;
#pragma unroll
          for (int s = 0; s < 20; ++s) {
            bool sw = ck > kv[s];
            ull tv = kv[s];
            kv[s] = sw ? ck : kv[s];
            ck = sw ? tv : ck;
          }
        }
      }
    }
    cnt = 0;
    u32 uc = ~(u32)(kv[19] >> 32);     // 0xFFFFFFFF when <20 items (no-op for min)
    atomicMin(&thrK[L], uc);
    u_cut = thrK[L];                   // <= own uc; stale-loose reads are safe
  };

  const int base = w * 512;
#pragma unroll 1
  for (int j0 = base; j0 < base + 512; j0 += 16) {
    {
      u32 hs = thrK[L];
      u_cut = hs < u_cut ? hs : u_cut;
    }
#pragma unroll
    for (int c = 0; c < 4; ++c) {
      float4 xv = *reinterpret_cast<const float4*>(xr + j0 + c*4);  // uniform -> s_load
      float4 yv = *reinterpret_cast<const float4*>(yr + j0 + c*4);
      const float xs[4] = {xv.x, xv.y, xv.z, xv.w};
      const float ys[4] = {yv.x, yv.y, yv.z, yv.w};
#pragma unroll
      for (int r = 0; r < 4; ++r) {
        float dx = xs[r] - px, dy = ys[r] - py;
        float s = dx*dx + dy*dy;
        u32 ub = __float_as_uint(s);
        if (ub <= u_cut) {
          pk1[cnt*512 + tid] = s;
          pi1[cnt*512 + tid] = (u16)(j0 + c*4 + r);
          ++cnt;
        }
      }
      if (__any(cnt >= 13)) flushK();   // cap 16: worst 12+4=16 (per-c check)
    }
  }
  flushK();

  __syncthreads();             // pbuf/thrK dead; switch to dump layout
#pragma unroll
  for (int k = 0; k < Kn; ++k) {
    ku[((size_t)w*64 + L)*20 + k] = (u32)(kv[k] >> 32);
    ki[((size_t)w*64 + L)*20 + k] = (u16)~(u32)kv[k];   // = j (real), 0xFFFF (empty)
  }
  __syncthreads();

  if (tid < 64) {              // 8-way merge per point
    const int p = tid;
    u32 hk_[8]; u16 hj_[8]; int pc[8];
#pragma unroll
    for (int q = 0; q < 8; ++q) {
      size_t bi = ((size_t)q*64 + p)*20;
      hk_[q] = ku[bi]; hj_[q] = ki[bi]; pc[q] = 0;
    }
    for (int k = 0; k < Kn; ++k) {
      u32 bk = hk_[0]; u16 bj = hj_[0]; int sel = 0;
#pragma unroll
      for (int q = 1; q < 8; ++q) {
        bool better = (hk_[q] > bk) || (hk_[q] == bk && hj_[q] < bj);
        if (better) { bk = hk_[q]; bj = hj_[q]; sel = q; }
      }
      midx[p*20 + k] = bj;
      int np_ = ++pc[sel];
      size_t bi = ((size_t)sel*64 + p)*20;
      hk_[sel] = (np_ < 20) ? ku[bi + np_] : 0u;
      hj_[sel] = (np_ < 20) ? ki[bi + np_] : (u16)0xFFFF;
    }
  }
  __syncthreads();             // midx ready; ku/ki dead

  // parallel neighbor-coordinate gather: 64*20 (x,y) pairs into LDS
  for (int i = tid; i < 64*Kn; i += 512) {
    int j = midx[i];
    nbr[i*2]     = xr[j];      // per-lane vector gather, L1-resident coords
    nbr[i*2 + 1] = yr[j];
  }
  __syncthreads();

  // phase 3: edgeconv1 — wave w handles points w*8 .. w*8+7, lane = channel o
  const int o = L;
  const float4 w1v = reinterpret_cast<const float4*>(W1)[o];
  const float sc = g1[o] / sqrtf(v1[o] + EPSf);
  const float mo = m1[o], bo = b1[o];

  for (int pi = 0; pi < 8; ++pi) {
    const int p = w*8 + pi;
    const int np = n0 + p;
    const float cx0 = xr[np], cx1 = yr[np];          // uniform
    const float cterm = (w1v.z - w1v.x)*cx0 + (w1v.w - w1v.y)*cx1;
    float xm = NEGINF;
#pragma unroll
    for (int k = 0; k < Kn; ++k) {
      float2 nv = *reinterpret_cast<const float2*>(&nbr[(p*20 + k)*2]);  // LDS broadcast
      float vv = w1v.x*nv.x + w1v.y*nv.y + cterm;
      float h = (vv - mo)*sc + bo;
      h = h >= 0.f ? h : SLOPE*h;
      xm = fmaxf(xm, h);
    }
    x1[(b*64 + o)*Np + np] = xm;
    __bf16 hb = (__bf16)xm;
    __bf16 lb = (__bf16)(xm - (float)hb);
    size_t tbase = ((size_t)b*Np + np)*64 + o;
    x1h[tbase] = hb;
    x1l[tbase] = lb;
    float s = xm*xm;
#pragma unroll
    for (int off = 1; off < 64; off <<= 1) s += __shfl_xor(s, off);
    if (L == 0) xx2[b*Np + np] = s;
  }
}

// ---------------- K2: knn2 — r3/r7-best configuration (200 µs measured), verbatim -----
__global__ __launch_bounds__(256, 2) void k2_knn2(
    const __bf16* __restrict__ xh, const __bf16* __restrict__ xl,
    const float* __restrict__ xx2, int* __restrict__ idx2)
{
  __shared__ ull smem[5120];   // 40 KB. ph1: sxx f32[4096] @0 | pk[15][256] @16384 | pi[15][256] @31744 | thr[16] @39424
                               // ph2: dump[4][64][20] @0
  float* sxx = (float*)smem;
  float* pk  = (float*)((char*)smem + 16384);   // [15][256] f32 keys, 15 KB
  u16*   pi  = (u16*)((char*)smem + 31744);     // [15][256] u16 idx, 7.5 KB
  u32*   thr = (u32*)((char*)smem + 39424);     // [16] row-shared sortable thresholds

  const int b = blockIdx.y;
  const int n0 = blockIdx.x * 16;
  const int tid = threadIdx.x;
  const int w = tid >> 6, L = tid & 63;
  const int L15 = L & 15, quad = L >> 4;

  for (int j = tid*4; j < Np; j += 1024)
    *reinterpret_cast<float4*>(&sxx[j]) = *reinterpret_cast<const float4*>(&xx2[(size_t)b*Np + j]);
  if (tid < 16) thr[tid] = 0u;

  // B operand: rows n0..n0+15
  const __bf16* Rh = xh + ((size_t)b*Np + n0)*64;
  const __bf16* Rl = xl + ((size_t)b*Np + n0)*64;
  bf16x8 rh0 = *reinterpret_cast<const bf16x8*>(Rh + L15*64 +  0 + quad*8);
  bf16x8 rh1 = *reinterpret_cast<const bf16x8*>(Rh + L15*64 + 32 + quad*8);
  bf16x8 rl0 = *reinterpret_cast<const bf16x8*>(Rl + L15*64 +  0 + quad*8);
  bf16x8 rl1 = *reinterpret_cast<const bf16x8*>(Rl + L15*64 + 32 + quad*8);

  const __bf16* Cbh = xh + (size_t)b*Np*64;
  const __bf16* Cbl = xl + (size_t)b*Np*64;

  ull kv[20];
#pragma unroll
  for (int s = 0; s < 20; ++s) kv[s] = 0ull;
  float fthresh = NEGINF;
  int cnt = 0;

  __syncthreads();   // sxx + thr ready

  auto flush = [&]() {
#pragma unroll 1
    for (int f0 = 0; f0 < 15; f0 += 4) {
      if (__all(f0 >= cnt)) break;
      float fv[4]; u32 ji[4];
#pragma unroll
      for (int u = 0; u < 4; ++u) {
        fv[u] = pk[(f0+u)*256 + tid];
        ji[u] = pi[(f0+u)*256 + tid];
      }
#pragma unroll
      for (int u = 0; u < 4; ++u) {
        int f = f0 + u;
        u32 uu = __float_as_uint(fv[u]);
        u32 hk = uu ^ ((u32)((int)uu >> 31) | 0x80000000u);
        ull key = (((ull)hk) << 32) | (u32)~ji[u];
        if (f < cnt && key > kv[19]) {
          ull ck = key;
#pragma unroll
          for (int s = 0; s < 20; ++s) {
            bool sw = ck > kv[s];
            ull tv = kv[s];
            kv[s] = sw ? ck : kv[s];
            ck = sw ? tv : ck;
          }
        }
      }
    }
    cnt = 0;
    ull t = kv[19];
    ull t2 = __shfl_xor(t, 16); t = t2 > t ? t2 : t;
    t2 = __shfl_xor(t, 32);     t = t2 > t ? t2 : t;
    if (t != 0ull && quad == 0) atomicMax(&thr[L15], (u32)(t >> 32));
    u32 hs = thr[L15];
    if (hs != 0u) {
      u32 u = (hs >> 31) ? (hs ^ 0x80000000u) : ~hs;
      fthresh = fmaxf(fthresh, __uint_as_float(u));
    }
  };

#pragma unroll 1
  for (int t = 0; t < 16; ++t) {
    {   // refresh row-shared threshold (stale-loose reads are safe)
      u32 hs = thr[L15];
      if (hs != 0u) {
        u32 u = (hs >> 31) ? (hs ^ 0x80000000u) : ~hs;
        fthresh = fmaxf(fthresh, __uint_as_float(u));
      }
    }
    const int tt = w + t*4;
    const int colbase = tt * 64;
    const __bf16* ph = Cbh + (size_t)colbase*64;
    const __bf16* pl = Cbl + (size_t)colbase*64;
    bf16x8 AH[4][2], AL[4][2];
#pragma unroll
    for (int s = 0; s < 4; ++s) {
      AH[s][0] = *reinterpret_cast<const bf16x8*>(ph + (s*16 + L15)*64 +  0 + quad*8);
      AH[s][1] = *reinterpret_cast<const bf16x8*>(ph + (s*16 + L15)*64 + 32 + quad*8);
      AL[s][0] = *reinterpret_cast<const bf16x8*>(pl + (s*16 + L15)*64 +  0 + quad*8);
      AL[s][1] = *reinterpret_cast<const bf16x8*>(pl + (s*16 + L15)*64 + 32 + quad*8);
    }

    f32x4 acc[4];
#pragma unroll
    for (int s = 0; s < 4; ++s) {
      acc[s] = (f32x4){0.f, 0.f, 0.f, 0.f};
      acc[s] = __builtin_amdgcn_mfma_f32_16x16x32_bf16(AH[s][0], rh0, acc[s], 0, 0, 0);
      acc[s] = __builtin_amdgcn_mfma_f32_16x16x32_bf16(AH[s][1], rh1, acc[s], 0, 0, 0);
      acc[s] = __builtin_amdgcn_mfma_f32_16x16x32_bf16(AH[s][0], rl0, acc[s], 0, 0, 0);
      acc[s] = __builtin_amdgcn_mfma_f32_16x16x32_bf16(AH[s][1], rl1, acc[s], 0, 0, 0);
      acc[s] = __builtin_amdgcn_mfma_f32_16x16x32_bf16(AL[s][0], rh0, acc[s], 0, 0, 0);
      acc[s] = __builtin_amdgcn_mfma_f32_16x16x32_bf16(AL[s][1], rh1, acc[s], 0, 0, 0);
    }

#pragma unroll
    for (int s = 0; s < 4; ++s) {
      float4 xv = *reinterpret_cast<const float4*>(&sxx[colbase + s*16 + quad*4]);
      const float xvr[4] = {xv.x, xv.y, xv.z, xv.w};
#pragma unroll
      for (int r = 0; r < 4; ++r) {
        float e = 2.0f*acc[s][r] - xvr[r];
        if (e >= fthresh) {
          pk[cnt*256 + tid] = e;
          pi[cnt*256 + tid] = (u16)(colbase + s*16 + quad*4 + r);
          ++cnt;
        }
      }
      if (__any(cnt >= 12)) flush();   // cap 15: max cnt 11+4=15
    }
  }
  flush();

  __syncthreads();   // sxx/pbuf dead -> dump layout
#pragma unroll
  for (int k = 0; k < Kn; ++k) smem[((size_t)w*64 + L)*20 + k] = kv[k];
  __syncthreads();

  if (tid < 16) {
    const int r = tid;
    ull h[16]; int pc[16];
#pragma unroll
    for (int i = 0; i < 16; ++i) {
      h[i] = smem[((size_t)(i>>2)*64 + (i&3)*16 + r)*20];
      pc[i] = 0;
    }
    size_t obase = ((size_t)b*Np + n0 + r)*Kn;
    for (int k = 0; k < Kn; ++k) {
      ull best = h[0]; int sel = 0;
#pragma unroll
      for (int i = 1; i < 16; ++i) if (h[i] > best) { best = h[i]; sel = i; }
      idx2[obase + k] = (int)~(u32)best;
      int np_ = ++pc[sel];
      h[sel] = (np_ < 20) ? smem[((size_t)(sel>>2)*64 + (sel&3)*16 + r)*20 + np_] : 0ull;
    }
  }
}

// ---------------- KY: precompute Za[n][o] = sc*(W2a . x1_n), Cn[n][o] ----------------
// grid (256, B): 16 points/block -> 4 blocks/CU TLP.
__global__ __launch_bounds__(256) void kY(
    const __bf16* __restrict__ xh, const __bf16* __restrict__ xl,
    const float* __restrict__ W2,
    const float* __restrict__ g2, const float* __restrict__ b2,
    const float* __restrict__ m2, const float* __restrict__ v2,
    float* __restrict__ Za, float* __restrict__ Cn)
{
  __shared__ float w2t[128*66];    // [c][o] padded, ~33 KB
  const int b = blockIdx.y;
  const int n0 = blockIdx.x * 16;
  const int tid = threadIdx.x;
  const int w = tid >> 6, L = tid & 63;

  for (int i = tid; i < 8192; i += 256) {
    int o = i >> 7, c = i & 127;
    w2t[c*66 + o] = W2[i];         // W2 row-major [64][128]
  }
  __syncthreads();

  const float sc = g2[L] / sqrtf(v2[L] + EPSf);
  const float cc = b2[L] - m2[L]*sc;

  for (int pi = 0; pi < 4; ++pi) {
    const int n = n0 + w*4 + pi;
    const size_t base = ((size_t)b*Np + n)*64;
    const float xv = (float)xh[base + L] + (float)xl[base + L];
    float ya = 0.f, yb = 0.f;
#pragma unroll
    for (int c = 0; c < 64; ++c) {
      float xc = __shfl(xv, c);
      ya += w2t[c*66 + L] * xc;          // W2[o][c]      (a-part)
      yb += w2t[(64 + c)*66 + L] * xc;   // W2[o][64+c]   (b-part)
    }
    float za = sc * ya;
    Za[base + L] = za;
    Cn[base + L] = sc * yb + cc - za;
  }
}

// ---------------- K3g: edgeconv2 gather — x2[o][n] = max_k lrelu(Za[j_k][o] + Cn[n][o]) ---
__global__ __launch_bounds__(256, 2) void k3_gather(
    const float* __restrict__ Za, const float* __restrict__ Cn,
    const int* __restrict__ idx2, float* __restrict__ x2)
{
  const int b = blockIdx.y;
  const int tid = threadIdx.x;
  const int w = tid >> 6, L = tid & 63;
  const int n = blockIdx.x*4 + w;

  const int* ip = idx2 + ((size_t)b*Np + n)*Kn;
  int jreg = (L < Kn) ? ip[L] : 0;
  const float c = Cn[((size_t)b*Np + n)*64 + L];
  float xm = NEGINF;
#pragma unroll
  for (int k = 0; k < Kn; ++k) {
    int j = __shfl(jreg, k);
    float hh = Za[((size_t)b*Np + j)*64 + L] + c;
    hh = hh >= 0.f ? hh : SLOPE*hh;
    xm = fmaxf(xm, hh);
  }
  x2[(b*64 + L)*Np + n] = xm;
}

// ---------------- K4: conv5 + per-block max over n — 2-way output split ----------------
// grid (nb x 2 halves, B), 512 thr. Block (nb, half) computes outputs
// o in [half*64, half*64+64): 8 groups x 8 outputs. 512 blocks = 2 blocks/CU
// (16 waves/CU, was 8) — xcr loads duplicated x2 but L1/L2-broadcast.
__global__ __launch_bounds__(512) void k4_conv5max(
    const float* __restrict__ x1, const float* __restrict__ x2,
    const float* __restrict__ W5,
    const float* __restrict__ g5, const float* __restrict__ b5,
    const float* __restrict__ m5, const float* __restrict__ v5,
    float* __restrict__ partials)  // (B,128,64)
{
  const int b = blockIdx.y;
  const int nb = blockIdx.x >> 1, half = blockIdx.x & 1;
  const int tid = threadIdx.x;
  const int p = tid & 63;
  const int g = __builtin_amdgcn_readfirstlane(tid >> 6);   // 0..7
  const int n = nb*64 + p;
  float xcr[128];
#pragma unroll
  for (int c = 0; c < 64; ++c) {
    xcr[c]    = x1[(b*64 + c)*Np + n];
    xcr[64+c] = x2[(b*64 + c)*Np + n];
  }
  for (int oi = 0; oi < 8; ++oi) {
    const int o = half*64 + g*8 + oi;
    const float* wr = W5 + o*128;
    float dot = 0.f;
#pragma unroll
    for (int c = 0; c < 128; c += 4) {
      float4 wv = *reinterpret_cast<const float4*>(wr + c);
      dot += wv.x*xcr[c] + wv.y*xcr[c+1] + wv.z*xcr[c+2] + wv.w*xcr[c+3];
    }
    float hv = (dot - m5[o])*(g5[o]/sqrtf(v5[o]+EPSf)) + b5[o];
    hv = hv >= 0.f ? hv : SLOPE*hv;
#pragma unroll
    for (int off = 1; off < 64; off <<= 1) hv = fmaxf(hv, __shfl_xor(hv, off));
    if (p == 0) partials[(b*128 + o)*64 + nb] = hv;
  }
}

// ---------------- K5: reduce partial maxima -> gmax, then t6 = W6a * gmax ----------------
// partials row (64 floats) is contiguous -> float4 x16 instead of 64 scalar loads.
__global__ __launch_bounds__(256) void k5_reduce_t6(
    const float* __restrict__ partials, const float* __restrict__ W6,
    float* __restrict__ t6)  // (B,256)
{
  __shared__ float sg[128];
  const int b = blockIdx.x;
  const int tid = threadIdx.x;
  if (tid < 128) {
    const float4* pr = reinterpret_cast<const float4*>(partials + ((size_t)b*128 + tid)*64);
    float m = NEGINF;
#pragma unroll
    for (int w = 0; w < 16; ++w) {
      float4 v = pr[w];
      m = fmaxf(m, fmaxf(fmaxf(v.x, v.y), fmaxf(v.z, v.w)));
    }
    sg[tid] = m;
  }
  __syncthreads();
  float a = 0.f;
#pragma unroll
  for (int c = 0; c < 128; c += 4) {
    float4 wv = *reinterpret_cast<const float4*>(W6 + tid*256 + c);
    a += wv.x*sg[c] + wv.y*sg[c+1] + wv.z*sg[c+2] + wv.w*sg[c+3];
  }
  t6[b*256 + tid] = a;
}

// ---------------- K6: conv6 (W6b part + t6) + bn + lrelu + W9 dot — 8-wave version ----
__global__ __launch_bounds__(512) void k6_conv6_out(
    const float* __restrict__ x1, const float* __restrict__ x2,
    const float* __restrict__ W6, const float* __restrict__ t6,
    const float* __restrict__ g6, const float* __restrict__ b6,
    const float* __restrict__ m6, const float* __restrict__ v6,
    const float* __restrict__ W9,
    float* __restrict__ out)
{
  __shared__ float red[8][64];
  const int b = blockIdx.y, nb = blockIdx.x;
  const int tid = threadIdx.x;
  const int p = tid & 63;
  const int g = __builtin_amdgcn_readfirstlane(tid >> 6);   // 0..7
  const int n = nb*64 + p;
  float xcr[128];
#pragma unroll
  for (int c = 0; c < 64; ++c) {
    xcr[c]    = x1[(b*64 + c)*Np + n];
    xcr[64+c] = x2[(b*64 + c)*Np + n];
  }
  float oacc = 0.f;
  for (int oi = 0; oi < 32; ++oi) {
    const int o = g*32 + oi;
    const float* wr = W6 + o*256 + 128;
    float dot = t6[b*256 + o];
#pragma unroll
    for (int c = 0; c < 128; c += 4) {
      float4 wv = *reinterpret_cast<const float4*>(wr + c);
      dot += wv.x*xcr[c] + wv.y*xcr[c+1] + wv.z*xcr[c+2] + wv.w*xcr[c+3];
    }
    float hv = (dot - m6[o])*(g6[o]/sqrtf(v6[o]+EPSf)) + b6[o];
    hv = hv >= 0.f ? hv : SLOPE*hv;
    oacc += W9[o]*hv;
  }
  red[g][p] = oacc;
  __syncthreads();
  if (tid < 64) {
    float s = 0.f;
#pragma unroll
    for (int q = 0; q < 8; ++q) s += red[q][tid];
    out[b*Np + nb*64 + tid] = s;
  }
}

extern "C" void kernel_launch(void* const* d_in, const int* in_sizes, int n_in,
                              void* d_out, int out_size, void* d_ws, size_t ws_size,
                              hipStream_t stream) {
  const float* x  = (const float*)d_in[0];
  const float* W1 = (const float*)d_in[1];
  const float* g1 = (const float*)d_in[2];
  const float* b1 = (const float*)d_in[3];
  const float* m1 = (const float*)d_in[4];
  const float* v1 = (const float*)d_in[5];
  const float* W2 = (const float*)d_in[6];
  const float* g2 = (const float*)d_in[7];
  const float* b2 = (const float*)d_in[8];
  const float* m2 = (const float*)d_in[9];
  const float* v2 = (const float*)d_in[10];
  const float* W5 = (const float*)d_in[11];
  const float* g5 = (const float*)d_in[12];
  const float* b5 = (const float*)d_in[13];
  const float* m5 = (const float*)d_in[14];
  const float* v5 = (const float*)d_in[15];
  const float* W6 = (const float*)d_in[16];
  const float* g6 = (const float*)d_in[17];
  const float* b6 = (const float*)d_in[18];
  const float* m6 = (const float*)d_in[19];
  const float* v6 = (const float*)d_in[20];
  const float* W9 = (const float*)d_in[21];
  float* out = (float*)d_out;

  float* F = (float*)d_ws;
  float*  x1    = F;                         // 1048576
  float*  xx2   = F + 1048576;               // 16384
  __bf16* x1h   = (__bf16*)(F + 1064960);    // 524288 float-slots
  __bf16* x1l   = (__bf16*)(F + 1589248);    // 524288
  float*  x2    = F + 2113536;               // 1048576
  int*    idx2  = (int*)(F + 3162112);       // 327680
  float*  t6    = F + 3489792;               // 1024
  float*  parts = F + 3490816;               // 32768
  float*  Za    = F + 3523584;               // 1048576
  float*  Cn    = F + 4572160;               // 1048576   (total 22.5 MB)

  k1_knn1_edge1<<<dim3(64,4), 512, 0, stream>>>(x, W1, g1, b1, m1, v1, x1, x1h, x1l, xx2);
  k2_knn2<<<dim3(256,4), 256, 0, stream>>>(x1h, x1l, xx2, idx2);
  kY<<<dim3(256,4), 256, 0, stream>>>(x1h, x1l, W2, g2, b2, m2, v2, Za, Cn);
  k3_gather<<<dim3(1024,4), 256, 0, stream>>>(Za, Cn, idx2, x2);
  k4_conv5max<<<dim3(128,4), 512, 0, stream>>>(x1, x2, W5, g5, b5, m5, v5, parts);
  k5_reduce_t6<<<4, 256, 0, stream>>>(parts, W6, t6);
  k6_conv6_out<<<dim3(64,4), 512, 0, stream>>>(x1, x2, W6, t6, g6, b6, m6, v6, W9, out);
}

// Round 11
// 520.191 us; speedup vs baseline: 1.0655x; 1.0090x over previous
//
#include <hip/hip_runtime.h>
#include <math.h>

#define NEGINF (-INFINITY)
constexpr int Np = 4096;
constexpr int Kn = 20;
constexpr float EPSf = 1e-5f;
constexpr float SLOPE = 0.2f;

typedef __bf16 bf16x8 __attribute__((ext_vector_type(8)));
typedef float f32x4 __attribute__((ext_vector_type(4)));
typedef unsigned long long ull;
typedef unsigned int u32;
typedef unsigned short u16;

// ---------------- K1: knn1 + edgeconv1 + fused kY (Za/Cn precompute) ----------------
// r8/r10 scan structure (best measured). grid (64, B), 512 thr (8 waves).
// Wave w scans 512 cols for the block's 64 points (lane L = point n0+L).
// Key = (~bits(d2)<<32) | ~j; cross-wave thrK via atomicMin. Overflow-safe flush
// (per-c check: trigger >=13, cap 16, worst 12+4=16).
// Phase 3 computes x1 AND the edgeconv2 precompute: lane L holds channel L of each
// point -> Ya/Yb = W2·x1 via __shfl dot against LDS-resident W2^T, writing
// Za = sc2*Ya and Cn = sc2*Yb + (b2-m2*sc2) - Za (replaces the standalone kY kernel:
// saves its launch, the 4 MB x1h/x1l re-read, and 3/4 of W2 staging).
// LDS 64000 B overlay:
//   scan:   pk1 f32[16][512] @0 | pi1 u16[16][512] @32768 | thrK u32[64] @49152
//   dump:   ku u32[8*64*20] @0 | ki u16[8*64*20] @40960 | midx u16[64*20] @61440
//   post:   nbr f32[64*20*2] @0 | w2t f32[128*66] @12288 (ends 46080) | midx @61440
__global__ __launch_bounds__(512, 2) void k1_knn1_edge1(
    const float* __restrict__ x, const float* __restrict__ W1,
    const float* __restrict__ g1, const float* __restrict__ b1,
    const float* __restrict__ m1, const float* __restrict__ v1,
    const float* __restrict__ W2,
    const float* __restrict__ g2, const float* __restrict__ b2,
    const float* __restrict__ m2, const float* __restrict__ v2,
    float* __restrict__ x1, __bf16* __restrict__ x1h, __bf16* __restrict__ x1l,
    float* __restrict__ xx2, float* __restrict__ Za, float* __restrict__ Cn)
{
  __shared__ u32 smem32[16000];   // 64000 B
  float* pk1  = (float*)smem32;                       // [16][512] f32
  u16*   pi1  = (u16*)((char*)smem32 + 32768);        // [16][512] u16
  u32*   thrK = (u32*)((char*)smem32 + 49152);        // [64]
  u32*   ku   = smem32;                               // dump keys  [8*64*20]
  u16*   ki   = (u16*)((char*)smem32 + 40960);        // dump idx   [8*64*20]
  u16*   midx = (u16*)((char*)smem32 + 61440);        // merged idx [64*20]
  float* nbr  = (float*)smem32;                       // gathered coords [64*20*2]
  float* w2t  = (float*)((char*)smem32 + 12288);      // W2^T [c][o] pad 66

  const int b = blockIdx.y;
  const int n0 = blockIdx.x * 64;
  const int tid = threadIdx.x;
  const int w = tid >> 6, L = tid & 63;
  const float* __restrict__ xr = x + (size_t)b*2*Np;
  const float* __restrict__ yr = xr + Np;

  const int n = n0 + L;
  const float px = xr[n], py = yr[n];

  if (tid < 64) thrK[tid] = 0xFFFFFFFFu;
  __syncthreads();

  ull kv[20];
#pragma unroll
  for (int s = 0; s < 20; ++s) kv[s] = 0ull;
  u32 u_cut = 0xFFFFFFFFu;
  int cnt = 0;

  auto flushK = [&]() {
#pragma unroll 1
    for (int f0 = 0; f0 < 16; f0 += 4) {
      if (__all(f0 >= cnt)) break;
      float fv[4]; u32 ji[4];
#pragma unroll
      for (int u = 0; u < 4; ++u) {
        fv[u] = pk1[(f0+u)*512 + tid];
        ji[u] = pi1[(f0+u)*512 + tid];
      }
#pragma unroll
      for (int u = 0; u < 4; ++u) {
        int f = f0 + u;
        ull key = (((ull)(~__float_as_uint(fv[u]))) << 32) | (u32)~ji[u];
        if (f < cnt && key > kv[19]) {
          ull ck = key;
#pragma unroll
          for (int s = 0; s < 20; ++s) {
            bool sw = ck > kv[s];
            ull tv = kv[s];
            kv[s] = sw ? ck : kv[s];
            ck = sw ? tv : ck;
          }
        }
      }
    }
    cnt = 0;
    u32 uc = ~(u32)(kv[19] >> 32);     // 0xFFFFFFFF when <20 items (no-op for min)
    atomicMin(&thrK[L], uc);
    u_cut = thrK[L];                   // <= own uc; stale-loose reads are safe
  };

  const int base = w * 512;
#pragma unroll 1
  for (int j0 = base; j0 < base + 512; j0 += 16) {
    {
      u32 hs = thrK[L];
      u_cut = hs < u_cut ? hs : u_cut;
    }
#pragma unroll
    for (int c = 0; c < 4; ++c) {
      float4 xv = *reinterpret_cast<const float4*>(xr + j0 + c*4);  // uniform -> s_load
      float4 yv = *reinterpret_cast<const float4*>(yr + j0 + c*4);
      const float xs[4] = {xv.x, xv.y, xv.z, xv.w};
      const float ys[4] = {yv.x, yv.y, yv.z, yv.w};
#pragma unroll
      for (int r = 0; r < 4; ++r) {
        float dx = xs[r] - px, dy = ys[r] - py;
        float s = dx*dx + dy*dy;
        u32 ub = __float_as_uint(s);
        if (ub <= u_cut) {
          pk1[cnt*512 + tid] = s;
          pi1[cnt*512 + tid] = (u16)(j0 + c*4 + r);
          ++cnt;
        }
      }
      if (__any(cnt >= 13)) flushK();   // cap 16: worst 12+4=16 (per-c check)
    }
  }
  flushK();

  __syncthreads();             // pbuf/thrK dead; switch to dump layout
#pragma unroll
  for (int k = 0; k < Kn; ++k) {
    ku[((size_t)w*64 + L)*20 + k] = (u32)(kv[k] >> 32);
    ki[((size_t)w*64 + L)*20 + k] = (u16)~(u32)kv[k];   // = j (real), 0xFFFF (empty)
  }
  __syncthreads();

  if (tid < 64) {              // 8-way merge per point
    const int p = tid;
    u32 hk_[8]; u16 hj_[8]; int pc[8];
#pragma unroll
    for (int q = 0; q < 8; ++q) {
      size_t bi = ((size_t)q*64 + p)*20;
      hk_[q] = ku[bi]; hj_[q] = ki[bi]; pc[q] = 0;
    }
    for (int k = 0; k < Kn; ++k) {
      u32 bk = hk_[0]; u16 bj = hj_[0]; int sel = 0;
#pragma unroll
      for (int q = 1; q < 8; ++q) {
        bool better = (hk_[q] > bk) || (hk_[q] == bk && hj_[q] < bj);
        if (better) { bk = hk_[q]; bj = hj_[q]; sel = q; }
      }
      midx[p*20 + k] = bj;
      int np_ = ++pc[sel];
      size_t bi = ((size_t)sel*64 + p)*20;
      hk_[sel] = (np_ < 20) ? ku[bi + np_] : 0u;
      hj_[sel] = (np_ < 20) ? ki[bi + np_] : (u16)0xFFFF;
    }
  }
  __syncthreads();             // midx ready; ku/ki dead

  // parallel: gather 64x20 neighbor (x,y) into nbr; stage W2^T into w2t
  for (int i = tid; i < 64*Kn; i += 512) {
    int j = midx[i];
    nbr[i*2]     = xr[j];
    nbr[i*2 + 1] = yr[j];
  }
  for (int i = tid; i < 8192; i += 512) {
    int o = i >> 7, c = i & 127;
    w2t[c*66 + o] = W2[i];     // W2 row-major [64][128]
  }
  __syncthreads();

  // phase 3: edgeconv1 + fused kY — wave w handles points w*8..w*8+7, lane = channel o
  const int o = L;
  const float4 w1v = reinterpret_cast<const float4*>(W1)[o];
  const float sc = g1[o] / sqrtf(v1[o] + EPSf);
  const float mo = m1[o], bo = b1[o];
  const float sc2 = g2[o] / sqrtf(v2[o] + EPSf);
  const float cc2 = b2[o] - m2[o]*sc2;

  for (int pi = 0; pi < 8; ++pi) {
    const int p = w*8 + pi;
    const int np = n0 + p;
    const float cx0 = xr[np], cx1 = yr[np];          // uniform
    const float cterm = (w1v.z - w1v.x)*cx0 + (w1v.w - w1v.y)*cx1;
    float xm = NEGINF;
#pragma unroll
    for (int k = 0; k < Kn; ++k) {
      float2 nv = *reinterpret_cast<const float2*>(&nbr[(p*20 + k)*2]);  // LDS broadcast
      float vv = w1v.x*nv.x + w1v.y*nv.y + cterm;
      float h = (vv - mo)*sc + bo;
      h = h >= 0.f ? h : SLOPE*h;
      xm = fmaxf(xm, h);
    }
    x1[(b*64 + o)*Np + np] = xm;
    __bf16 hb = (__bf16)xm;
    __bf16 lb = (__bf16)(xm - (float)hb);
    size_t tbase = ((size_t)b*Np + np)*64 + o;
    x1h[tbase] = hb;
    x1l[tbase] = lb;
    float s = xm*xm;
#pragma unroll
    for (int off = 1; off < 64; off <<= 1) s += __shfl_xor(s, off);
    if (L == 0) xx2[b*Np + np] = s;

    // fused kY: Ya/Yb for this point (lane L holds channel L; shfl broadcasts)
    float ya = 0.f, yb = 0.f;
#pragma unroll
    for (int c = 0; c < 64; ++c) {
      float xc = __shfl(xm, c);
      ya += w2t[c*66 + o] * xc;          // W2[o][c]      (a-part)
      yb += w2t[(64 + c)*66 + o] * xc;   // W2[o][64+c]   (b-part)
    }
    float za = sc2 * ya;
    Za[tbase] = za;
    Cn[tbase] = sc2 * yb + cc2 - za;
  }
}

// ---------------- K2: knn2 — r3/r7-best configuration (200 µs measured), verbatim -----
__global__ __launch_bounds__(256, 2) void k2_knn2(
    const __bf16* __restrict__ xh, const __bf16* __restrict__ xl,
    const float* __restrict__ xx2, int* __restrict__ idx2)
{
  __shared__ ull smem[5120];   // 40 KB. ph1: sxx f32[4096] @0 | pk[15][256] @16384 | pi[15][256] @31744 | thr[16] @39424
                               // ph2: dump[4][64][20] @0
  float* sxx = (float*)smem;
  float* pk  = (float*)((char*)smem + 16384);   // [15][256] f32 keys, 15 KB
  u16*   pi  = (u16*)((char*)smem + 31744);     // [15][256] u16 idx, 7.5 KB
  u32*   thr = (u32*)((char*)smem + 39424);     // [16] row-shared sortable thresholds

  const int b = blockIdx.y;
  const int n0 = blockIdx.x * 16;
  const int tid = threadIdx.x;
  const int w = tid >> 6, L = tid & 63;
  const int L15 = L & 15, quad = L >> 4;

  for (int j = tid*4; j < Np; j += 1024)
    *reinterpret_cast<float4*>(&sxx[j]) = *reinterpret_cast<const float4*>(&xx2[(size_t)b*Np + j]);
  if (tid < 16) thr[tid] = 0u;

  // B operand: rows n0..n0+15
  const __bf16* Rh = xh + ((size_t)b*Np + n0)*64;
  const __bf16* Rl = xl + ((size_t)b*Np + n0)*64;
  bf16x8 rh0 = *reinterpret_cast<const bf16x8*>(Rh + L15*64 +  0 + quad*8);
  bf16x8 rh1 = *reinterpret_cast<const bf16x8*>(Rh + L15*64 + 32 + quad*8);
  bf16x8 rl0 = *reinterpret_cast<const bf16x8*>(Rl + L15*64 +  0 + quad*8);
  bf16x8 rl1 = *reinterpret_cast<const bf16x8*>(Rl + L15*64 + 32 + quad*8);

  const __bf16* Cbh = xh + (size_t)b*Np*64;
  const __bf16* Cbl = xl + (size_t)b*Np*64;

  ull kv[20];
#pragma unroll
  for (int s = 0; s < 20; ++s) kv[s] = 0ull;
  float fthresh = NEGINF;
  int cnt = 0;

  __syncthreads();   // sxx + thr ready

  auto flush = [&]() {
#pragma unroll 1
    for (int f0 = 0; f0 < 15; f0 += 4) {
      if (__all(f0 >= cnt)) break;
      float fv[4]; u32 ji[4];
#pragma unroll
      for (int u = 0; u < 4; ++u) {
        fv[u] = pk[(f0+u)*256 + tid];
        ji[u] = pi[(f0+u)*256 + tid];
      }
#pragma unroll
      for (int u = 0; u < 4; ++u) {
        int f = f0 + u;
        u32 uu = __float_as_uint(fv[u]);
        u32 hk = uu ^ ((u32)((int)uu >> 31) | 0x80000000u);
        ull key = (((ull)hk) << 32) | (u32)~ji[u];
        if (f < cnt && key > kv[19]) {
          ull ck = key;
#pragma unroll
          for (int s = 0; s < 20; ++s) {
            bool sw = ck > kv[s];
            ull tv = kv[s];
            kv[s] = sw ? ck : kv[s];
            ck = sw ? tv : ck;
          }
        }
      }
    }
    cnt = 0;
    ull t = kv[19];
    ull t2 = __shfl_xor(t, 16); t = t2 > t ? t2 : t;
    t2 = __shfl_xor(t, 32);     t = t2 > t ? t2 : t;
    if (t != 0ull && quad == 0) atomicMax(&thr[L15], (u32)(t >> 32));
    u32 hs = thr[L15];
    if (hs != 0u) {
      u32 u = (hs >> 31) ? (hs ^ 0x80000000u) : ~hs;
      fthresh = fmaxf(fthresh, __uint_as_float(u));
    }
  };

#pragma unroll 1
  for (int t = 0; t < 16; ++t) {
    {   // refresh row-shared threshold (stale-loose reads are safe)
      u32 hs = thr[L15];
      if (hs != 0u) {
        u32 u = (hs >> 31) ? (hs ^ 0x80000000u) : ~hs;
        fthresh = fmaxf(fthresh, __uint_as_float(u));
      }
    }
    const int tt = w + t*4;
    const int colbase = tt * 64;
    const __bf16* ph = Cbh + (size_t)colbase*64;
    const __bf16* pl = Cbl + (size_t)colbase*64;
    bf16x8 AH[4][2], AL[4][2];
#pragma unroll
    for (int s = 0; s < 4; ++s) {
      AH[s][0] = *reinterpret_cast<const bf16x8*>(ph + (s*16 + L15)*64 +  0 + quad*8);
      AH[s][1] = *reinterpret_cast<const bf16x8*>(ph + (s*16 + L15)*64 + 32 + quad*8);
      AL[s][0] = *reinterpret_cast<const bf16x8*>(pl + (s*16 + L15)*64 +  0 + quad*8);
      AL[s][1] = *reinterpret_cast<const bf16x8*>(pl + (s*16 + L15)*64 + 32 + quad*8);
    }

    f32x4 acc[4];
#pragma unroll
    for (int s = 0; s < 4; ++s) {
      acc[s] = (f32x4){0.f, 0.f, 0.f, 0.f};
      acc[s] = __builtin_amdgcn_mfma_f32_16x16x32_bf16(AH[s][0], rh0, acc[s], 0, 0, 0);
      acc[s] = __builtin_amdgcn_mfma_f32_16x16x32_bf16(AH[s][1], rh1, acc[s], 0, 0, 0);
      acc[s] = __builtin_amdgcn_mfma_f32_16x16x32_bf16(AH[s][0], rl0, acc[s], 0, 0, 0);
      acc[s] = __builtin_amdgcn_mfma_f32_16x16x32_bf16(AH[s][1], rl1, acc[s], 0, 0, 0);
      acc[s] = __builtin_amdgcn_mfma_f32_16x16x32_bf16(AL[s][0], rh0, acc[s], 0, 0, 0);
      acc[s] = __builtin_amdgcn_mfma_f32_16x16x32_bf16(AL[s][1], rh1, acc[s], 0, 0, 0);
    }

#pragma unroll
    for (int s = 0; s < 4; ++s) {
      float4 xv = *reinterpret_cast<const float4*>(&sxx[colbase + s*16 + quad*4]);
      const float xvr[4] = {xv.x, xv.y, xv.z, xv.w};
#pragma unroll
      for (int r = 0; r < 4; ++r) {
        float e = 2.0f*acc[s][r] - xvr[r];
        if (e >= fthresh) {
          pk[cnt*256 + tid] = e;
          pi[cnt*256 + tid] = (u16)(colbase + s*16 + quad*4 + r);
          ++cnt;
        }
      }
      if (__any(cnt >= 12)) flush();   // cap 15: max cnt 11+4=15
    }
  }
  flush();

  __syncthreads();   // sxx/pbuf dead -> dump layout
#pragma unroll
  for (int k = 0; k < Kn; ++k) smem[((size_t)w*64 + L)*20 + k] = kv[k];
  __syncthreads();

  if (tid < 16) {
    const int r = tid;
    ull h[16]; int pc[16];
#pragma unroll
    for (int i = 0; i < 16; ++i) {
      h[i] = smem[((size_t)(i>>2)*64 + (i&3)*16 + r)*20];
      pc[i] = 0;
    }
    size_t obase = ((size_t)b*Np + n0 + r)*Kn;
    for (int k = 0; k < Kn; ++k) {
      ull best = h[0]; int sel = 0;
#pragma unroll
      for (int i = 1; i < 16; ++i) if (h[i] > best) { best = h[i]; sel = i; }
      idx2[obase + k] = (int)~(u32)best;
      int np_ = ++pc[sel];
      h[sel] = (np_ < 20) ? smem[((size_t)(sel>>2)*64 + (sel&3)*16 + r)*20 + np_] : 0ull;
    }
  }
}

// ---------------- K3g: edgeconv2 gather — x2[o][n] = max_k lrelu(Za[j_k][o] + Cn[n][o]) ---
__global__ __launch_bounds__(256, 2) void k3_gather(
    const float* __restrict__ Za, const float* __restrict__ Cn,
    const int* __restrict__ idx2, float* __restrict__ x2)
{
  const int b = blockIdx.y;
  const int tid = threadIdx.x;
  const int w = tid >> 6, L = tid & 63;
  const int n = blockIdx.x*4 + w;

  const int* ip = idx2 + ((size_t)b*Np + n)*Kn;
  int jreg = (L < Kn) ? ip[L] : 0;
  const float c = Cn[((size_t)b*Np + n)*64 + L];
  float xm = NEGINF;
#pragma unroll
  for (int k = 0; k < Kn; ++k) {
    int j = __shfl(jreg, k);
    float hh = Za[((size_t)b*Np + j)*64 + L] + c;
    hh = hh >= 0.f ? hh : SLOPE*hh;
    xm = fmaxf(xm, hh);
  }
  x2[(b*64 + L)*Np + n] = xm;
}

// ---------------- K4: conv5 + per-block max over n — 2-way output split ----------------
__global__ __launch_bounds__(512) void k4_conv5max(
    const float* __restrict__ x1, const float* __restrict__ x2,
    const float* __restrict__ W5,
    const float* __restrict__ g5, const float* __restrict__ b5,
    const float* __restrict__ m5, const float* __restrict__ v5,
    float* __restrict__ partials)  // (B,128,64)
{
  const int b = blockIdx.y;
  const int nb = blockIdx.x >> 1, half = blockIdx.x & 1;
  const int tid = threadIdx.x;
  const int p = tid & 63;
  const int g = __builtin_amdgcn_readfirstlane(tid >> 6);   // 0..7
  const int n = nb*64 + p;
  float xcr[128];
#pragma unroll
  for (int c = 0; c < 64; ++c) {
    xcr[c]    = x1[(b*64 + c)*Np + n];
    xcr[64+c] = x2[(b*64 + c)*Np + n];
  }
  for (int oi = 0; oi < 8; ++oi) {
    const int o = half*64 + g*8 + oi;
    const float* wr = W5 + o*128;
    float dot = 0.f;
#pragma unroll
    for (int c = 0; c < 128; c += 4) {
      float4 wv = *reinterpret_cast<const float4*>(wr + c);
      dot += wv.x*xcr[c] + wv.y*xcr[c+1] + wv.z*xcr[c+2] + wv.w*xcr[c+3];
    }
    float hv = (dot - m5[o])*(g5[o]/sqrtf(v5[o]+EPSf)) + b5[o];
    hv = hv >= 0.f ? hv : SLOPE*hv;
#pragma unroll
    for (int off = 1; off < 64; off <<= 1) hv = fmaxf(hv, __shfl_xor(hv, off));
    if (p == 0) partials[(b*128 + o)*64 + nb] = hv;
  }
}

// ---------------- K5: reduce partial maxima -> gmax, then t6 = W6a * gmax ----------------
__global__ __launch_bounds__(256) void k5_reduce_t6(
    const float* __restrict__ partials, const float* __restrict__ W6,
    float* __restrict__ t6)  // (B,256)
{
  __shared__ float sg[128];
  const int b = blockIdx.x;
  const int tid = threadIdx.x;
  if (tid < 128) {
    const float4* pr = reinterpret_cast<const float4*>(partials + ((size_t)b*128 + tid)*64);
    float m = NEGINF;
#pragma unroll
    for (int w = 0; w < 16; ++w) {
      float4 v = pr[w];
      m = fmaxf(m, fmaxf(fmaxf(v.x, v.y), fmaxf(v.z, v.w)));
    }
    sg[tid] = m;
  }
  __syncthreads();
  float a = 0.f;
#pragma unroll
  for (int c = 0; c < 128; c += 4) {
    float4 wv = *reinterpret_cast<const float4*>(W6 + tid*256 + c);
    a += wv.x*sg[c] + wv.y*sg[c+1] + wv.z*sg[c+2] + wv.w*sg[c+3];
  }
  t6[b*256 + tid] = a;
}

// ---------------- K6: conv6 + W9 dot — 2-way output split, atomicAdd combine ----------
// grid (nb x 2 halves, B), 512 thr. Block (nb, half) covers o in [half*128, half*128+128):
// 8 groups x 16 outputs -> 2 blocks/CU (16 waves/CU). out zeroed via hipMemsetAsync;
// halves combine with one atomicAdd per (block, output element).
__global__ __launch_bounds__(512) void k6_conv6_out(
    const float* __restrict__ x1, const float* __restrict__ x2,
    const float* __restrict__ W6, const float* __restrict__ t6,
    const float* __restrict__ g6, const float* __restrict__ b6,
    const float* __restrict__ m6, const float* __restrict__ v6,
    const float* __restrict__ W9,
    float* __restrict__ out)
{
  __shared__ float red[8][64];
  const int b = blockIdx.y;
  const int nb = blockIdx.x >> 1, half = blockIdx.x & 1;
  const int tid = threadIdx.x;
  const int p = tid & 63;
  const int g = __builtin_amdgcn_readfirstlane(tid >> 6);   // 0..7
  const int n = nb*64 + p;
  float xcr[128];
#pragma unroll
  for (int c = 0; c < 64; ++c) {
    xcr[c]    = x1[(b*64 + c)*Np + n];
    xcr[64+c] = x2[(b*64 + c)*Np + n];
  }
  float oacc = 0.f;
  for (int oi = 0; oi < 16; ++oi) {
    const int o = half*128 + g*16 + oi;
    const float* wr = W6 + o*256 + 128;
    float dot = t6[b*256 + o];
#pragma unroll
    for (int c = 0; c < 128; c += 4) {
      float4 wv = *reinterpret_cast<const float4*>(wr + c);
      dot += wv.x*xcr[c] + wv.y*xcr[c+1] + wv.z*xcr[c+2] + wv.w*xcr[c+3];
    }
    float hv = (dot - m6[o])*(g6[o]/sqrtf(v6[o]+EPSf)) + b6[o];
    hv = hv >= 0.f ? hv : SLOPE*hv;
    oacc += W9[o]*hv;
  }
  red[g][p] = oacc;
  __syncthreads();
  if (tid < 64) {
    float s = 0.f;
#pragma unroll
    for (int q = 0; q < 8; ++q) s += red[q][tid];
    atomicAdd(&out[b*Np + nb*64 + tid], s);
  }
}

extern "C" void kernel_launch(void* const* d_in, const int* in_sizes, int n_in,
                              void* d_out, int out_size, void* d_ws, size_t ws_size,
                              hipStream_t stream) {
  const float* x  = (const float*)d_in[0];
  const float* W1 = (const float*)d_in[1];
  const float* g1 = (const float*)d_in[2];
  const float* b1 = (const float*)d_in[3];
  const float* m1 = (const float*)d_in[4];
  const float* v1 = (const float*)d_in[5];
  const float* W2 = (const float*)d_in[6];
  const float* g2 = (const float*)d_in[7];
  const float* b2 = (const float*)d_in[8];
  const float* m2 = (const float*)d_in[9];
  const float* v2 = (const float*)d_in[10];
  const float* W5 = (const float*)d_in[11];
  const float* g5 = (const float*)d_in[12];
  const float* b5 = (const float*)d_in[13];
  const float* m5 = (const float*)d_in[14];
  const float* v5 = (const float*)d_in[15];
  const float* W6 = (const float*)d_in[16];
  const float* g6 = (const float*)d_in[17];
  const float* b6 = (const float*)d_in[18];
  const float* m6 = (const float*)d_in[19];
  const float* v6 = (const float*)d_in[20];
  const float* W9 = (const float*)d_in[21];
  float* out = (float*)d_out;

  float* F = (float*)d_ws;
  float*  x1    = F;                         // 1048576
  float*  xx2   = F + 1048576;               // 16384
  __bf16* x1h   = (__bf16*)(F + 1064960);    // 524288 float-slots
  __bf16* x1l   = (__bf16*)(F + 1589248);    // 524288
  float*  x2    = F + 2113536;               // 1048576
  int*    idx2  = (int*)(F + 3162112);       // 327680
  float*  t6    = F + 3489792;               // 1024
  float*  parts = F + 3490816;               // 32768
  float*  Za    = F + 3523584;               // 1048576
  float*  Cn    = F + 4572160;               // 1048576   (total 22.5 MB)

  k1_knn1_edge1<<<dim3(64,4), 512, 0, stream>>>(x, W1, g1, b1, m1, v1,
                                                W2, g2, b2, m2, v2,
                                                x1, x1h, x1l, xx2, Za, Cn);
  k2_knn2<<<dim3(256,4), 256, 0, stream>>>(x1h, x1l, xx2, idx2);
  k3_gather<<<dim3(1024,4), 256, 0, stream>>>(Za, Cn, idx2, x2);
  k4_conv5max<<<dim3(128,4), 512, 0, stream>>>(x1, x2, W5, g5, b5, m5, v5, parts);
  k5_reduce_t6<<<4, 256, 0, stream>>>(parts, W6, t6);
  hipMemsetAsync(out, 0, out_size, stream);
  k6_conv6_out<<<dim3(128,4), 512, 0, stream>>>(x1, x2, W6, t6, g6, b6, m6, v6, W9, out);
}